// Round 3
// baseline (692.459 us; speedup 1.0000x reference)
//
#include <hip/hip_runtime.h>
#include <math.h>

// Problem constants (B=4,S=1024 -> T=4096; D=2048; E=16; H=1024; top-2)
#define T_TOK 4096
#define DDIM  2048
#define HDIM  1024
#define NEXP  16
#define CAP   4096
#define GBM   128
#define GBN   128
#define GBK   64     // bf16 elems per K-tile
#define MAX_TILES 80 // sum ceil(cnt_e/128) <= 8192/128 + 16

typedef __attribute__((ext_vector_type(8))) short  short8;
typedef __attribute__((ext_vector_type(4))) float  floatx4;

__device__ __forceinline__ unsigned short f2bf(float f) {
    unsigned int u = __float_as_uint(f);
    u += 0x7fffu + ((u >> 16) & 1u);   // round-to-nearest-even
    return (unsigned short)(u >> 16);
}
__device__ __forceinline__ float bf2f(unsigned short u) {
    return __uint_as_float((unsigned int)u << 16);
}

__device__ __forceinline__ void gl_lds16(const void* g, void* l) {
    __builtin_amdgcn_global_load_lds(
        (const __attribute__((address_space(1))) unsigned int*)g,
        (__attribute__((address_space(3))) unsigned int*)l,
        16, 0, 0);
}

// ---------------------------------------------------------------------------
// gate_kernel: 1024 blocks x 256 thr; one wave per token (4 tokens/block).
// Computes sigmoid gating, top-2, token lists, and x -> bf16 (xbf).
// The 245us weight-transpose prep is GONE: conversion+transpose now fused
// into the GEMM B-staging (three prep variants all plateaued at 1.3 TB/s).
// ---------------------------------------------------------------------------
__global__ __launch_bounds__(256) void gate_kernel(
    const float* __restrict__ x, const float* __restrict__ Wg,
    const float* __restrict__ bias,
    int* __restrict__ counts, int* __restrict__ tok_list,
    int4* __restrict__ tinfo, float2* __restrict__ wcomb,
    unsigned short* __restrict__ xbf)
{
    int tb   = blockIdx.x;                 // 0..1023
    int wv   = threadIdx.x >> 6;
    int lane = threadIdx.x & 63;
    int t    = tb * 4 + wv;

    const float4* xp4 = (const float4*)x + (size_t)t * (DDIM / 4);
    ushort4* xbp4 = (ushort4*)(xbf + (size_t)t * DDIM);
    const float4* wg4 = (const float4*)Wg;

    float acc[NEXP];
#pragma unroll
    for (int e = 0; e < NEXP; ++e) acc[e] = 0.f;

    for (int it = 0; it < DDIM / 4 / 64; ++it) {
        int d4 = it * 64 + lane;
        float4 xv = xp4[d4];
        ushort4 xs;
        xs.x = f2bf(xv.x); xs.y = f2bf(xv.y);
        xs.z = f2bf(xv.z); xs.w = f2bf(xv.w);
        xbp4[d4] = xs;
#pragma unroll
        for (int e = 0; e < NEXP; ++e) {
            float4 wvv = wg4[e * (DDIM / 4) + d4];
            acc[e] += xv.x * wvv.x + xv.y * wvv.y + xv.z * wvv.z + xv.w * wvv.w;
        }
    }
#pragma unroll
    for (int e = 0; e < NEXP; ++e) {
        float v = acc[e];
#pragma unroll
        for (int off = 32; off > 0; off >>= 1) v += __shfl_xor(v, off, 64);
        acc[e] = v;
    }
    if (lane == 0) {
        float s[NEXP];
#pragma unroll
        for (int e = 0; e < NEXP; ++e)
            s[e] = 1.f / (1.f + expf(-(acc[e] + bias[e])));
        int i0 = 0;
#pragma unroll
        for (int e = 1; e < NEXP; ++e) if (s[e] > s[i0]) i0 = e;
        int i1 = (i0 == 0) ? 1 : 0;
        for (int e = 0; e < NEXP; ++e)
            if (e != i0 && s[e] > s[i1]) i1 = e;
        float denom = s[i0] + s[i1] + 1e-6f;
        int p0 = atomicAdd(&counts[i0], 1);
        tok_list[i0 * CAP + p0] = t;
        int p1 = atomicAdd(&counts[i1], 1);
        tok_list[i1 * CAP + p1] = t;
        tinfo[t] = make_int4(i0, p0, i1, p1);
        wcomb[t] = make_float2(s[i0] / denom, s[i1] / denom);
    }
}

// ---------------------------------------------------------------------------
// scan: single wave, shuffle prefix-scan.
// ---------------------------------------------------------------------------
__global__ void scan_kernel(const int* __restrict__ counts, int* __restrict__ offsets,
                            int* __restrict__ ntiles, int* __restrict__ tile_e,
                            int* __restrict__ tile_mt)
{
    int lane = threadIdx.x;                         // 64 threads
    int c = (lane < NEXP) ? counts[lane] : 0;
    int incl = c;
#pragma unroll
    for (int d = 1; d < 64; d <<= 1) {
        int v = __shfl_up(incl, d, 64);
        if (lane >= d) incl += v;
    }
    if (lane < NEXP) offsets[lane] = incl - c;
    if (lane == NEXP - 1) offsets[NEXP] = incl;

    int nt_e = (lane < NEXP) ? ((c + GBM - 1) / GBM) : 0;
    int tincl = nt_e;
#pragma unroll
    for (int d = 1; d < 64; d <<= 1) {
        int v = __shfl_up(tincl, d, 64);
        if (lane >= d) tincl += v;
    }
    int tbase = tincl - nt_e;
    if (lane < NEXP) {
        for (int i = 0; i < nt_e; ++i) {
            tile_e[tbase + i]  = lane;
            tile_mt[tbase + i] = i;
        }
        if (lane == NEXP - 1) *ntiles = tbase + nt_e;
    }
}

// ---------------------------------------------------------------------------
// Fused B-staging GEMM core idea (both GEMMs):
//   A: bf16 activations via global_load_lds (linear LDS, pre-swizzled gsrc,
//      read with kcs = (ks*4+fq) ^ (row&7))                 -- unchanged.
//   B: fp32 weights [k][n] loaded per-lane as 8 float4 from 4 k-rows,
//      register 4x4 transpose + RNE f2bf pack -> b64 k-packed LDS writes at
//      granule slot c ^ f2(n), f2(n) = ((n>>3)^n)&7  (4 words/bank = b64
//      floor, 2-way free); fragment read kcs = (ks*4+fq) ^ f2(row)
//      (8 words/bank over b128's 4 cycles = free).
//   Pipelining (T14): issue next-tile A gl_lds + B reg-loads BEFORE the MFMA
//   phase; pack+ds_write into the idle nxt buffer AFTER (vmcnt hidden under
//   MFMA; nxt's last readers finished before this iteration's barrier).
// ---------------------------------------------------------------------------

// up_gemm: h = silu(Xg @ W1_e) -> bf16 hbuf.  B = W1 [e][k=DDIM][n=HDIM] fp32.
__global__ __launch_bounds__(256) void up_gemm(
    const unsigned short* __restrict__ xbf, const float* __restrict__ W1,
    const int* __restrict__ counts, const int* __restrict__ offsets,
    const int* __restrict__ ntiles, const int* __restrict__ tile_e,
    const int* __restrict__ tile_mt,
    const int* __restrict__ tok_list, unsigned short* __restrict__ hbuf)
{
    int idx = blockIdx.x;
    if (idx >= *ntiles) return;
    int e   = tile_e[idx];
    int mt  = tile_mt[idx];
    int cnt = counts[e];
    int nbase = blockIdx.y * GBN;
    const int N = HDIM;                       // B row length (n)

    __shared__ __align__(16) unsigned short As[2][GBM * GBK];
    __shared__ __align__(16) unsigned short Bs[2][GBN * GBK];

    int tid = threadIdx.x, lane = tid & 63, wv = tid >> 6;
    int kcL = ((lane & 7) ^ ((lane >> 3) & 7)) * 8;
    int hbase = offsets[e];

    // ---- A source (tokens), unchanged ----
    const unsigned short* gA[4];
#pragma unroll
    for (int j = 0; j < 4; ++j) {
        int row = wv * 32 + j * 8 + (lane >> 3);
        int m = mt * GBM + row; if (m >= cnt) m = cnt - 1;
        int tok = tok_list[e * CAP + m];
        gA[j] = xbf + (size_t)tok * DDIM + kcL;
    }

    // ---- B source (fp32 weights, [k][n]) ----
    const float* wB = W1 + (size_t)e * DDIM * HDIM;
    int ng = lane >> 2, kg = lane & 3;        // 16 n-groups x 4 k-groups
    int nh = (wv & 1) * 64, kh = (wv >> 1) * 32;
    int nloc = nh + ng * 4;                   // lane's first n (4 consecutive)
    const float* gBbase = wB + (size_t)(kh + kg * 4) * N + nbase + nloc;
    int cbase = (kh >> 3) + (kg >> 1);        // granule base (+ i4*2)
    int koff  = (kg & 1) * 4;                 // short offset within granule

    int fr = lane & 15, fq = lane >> 4;
    int wm = (wv & 1) * 64, wn = (wv >> 1) * 64;

    floatx4 acc[4][4];
#pragma unroll
    for (int i = 0; i < 4; ++i)
#pragma unroll
        for (int j = 0; j < 4; ++j) acc[i][j] = (floatx4){0.f, 0.f, 0.f, 0.f};

    float4 bv[8];
#pragma unroll
    for (int j = 0; j < 4; ++j)
        gl_lds16(gA[j], &As[0][((wv * 4 + j) * 64 + lane) * 8]);
#pragma unroll
    for (int i4 = 0; i4 < 2; ++i4)
#pragma unroll
        for (int ld = 0; ld < 4; ++ld)
            bv[i4 * 4 + ld] = *(const float4*)(gBbase + (size_t)(i4 * 16 + ld) * N);
    // pack + write B[0]
#pragma unroll
    for (int i4 = 0; i4 < 2; ++i4) {
#pragma unroll
        for (int j = 0; j < 4; ++j) {
            unsigned int lo = (unsigned int)f2bf(((const float*)&bv[i4 * 4 + 0])[j])
                            | ((unsigned int)f2bf(((const float*)&bv[i4 * 4 + 1])[j]) << 16);
            unsigned int hi = (unsigned int)f2bf(((const float*)&bv[i4 * 4 + 2])[j])
                            | ((unsigned int)f2bf(((const float*)&bv[i4 * 4 + 3])[j]) << 16);
            int row = nloc + j;
            int gsl = (cbase + i4 * 2) ^ (((row >> 3) ^ row) & 7);
            *(uint2*)&Bs[0][row * GBK + gsl * 8 + koff] = make_uint2(lo, hi);
        }
    }

    const int NK = DDIM / GBK;
    for (int i = 0; i < NK; ++i) {
        int cur = i & 1, nxt = cur ^ 1;
        __syncthreads();
        if (i + 1 < NK) {
            int k0 = (i + 1) * GBK;
#pragma unroll
            for (int j = 0; j < 4; ++j)
                gl_lds16(gA[j] + k0, &As[nxt][((wv * 4 + j) * 64 + lane) * 8]);
#pragma unroll
            for (int i4 = 0; i4 < 2; ++i4)
#pragma unroll
                for (int ld = 0; ld < 4; ++ld)
                    bv[i4 * 4 + ld] = *(const float4*)(gBbase + (size_t)(k0 + i4 * 16 + ld) * N);
        }
#pragma unroll
        for (int ks = 0; ks < 2; ++ks) {
            short8 af[4], bfr[4];
#pragma unroll
            for (int mi = 0; mi < 4; ++mi) {
                int row = wm + mi * 16 + fr;
                int kcs = (ks * 4 + fq) ^ (row & 7);
                af[mi] = *(const short8*)&As[cur][row * GBK + kcs * 8];
            }
#pragma unroll
            for (int ni = 0; ni < 4; ++ni) {
                int row = wn + ni * 16 + fr;
                int kcs = (ks * 4 + fq) ^ (((row >> 3) ^ row) & 7);
                bfr[ni] = *(const short8*)&Bs[cur][row * GBK + kcs * 8];
            }
#pragma unroll
            for (int mi = 0; mi < 4; ++mi)
#pragma unroll
                for (int ni = 0; ni < 4; ++ni)
                    acc[mi][ni] = __builtin_amdgcn_mfma_f32_16x16x32_bf16(
                        af[mi], bfr[ni], acc[mi][ni], 0, 0, 0);
        }
        if (i + 1 < NK) {
#pragma unroll
            for (int i4 = 0; i4 < 2; ++i4) {
#pragma unroll
                for (int j = 0; j < 4; ++j) {
                    unsigned int lo = (unsigned int)f2bf(((const float*)&bv[i4 * 4 + 0])[j])
                                    | ((unsigned int)f2bf(((const float*)&bv[i4 * 4 + 1])[j]) << 16);
                    unsigned int hi = (unsigned int)f2bf(((const float*)&bv[i4 * 4 + 2])[j])
                                    | ((unsigned int)f2bf(((const float*)&bv[i4 * 4 + 3])[j]) << 16);
                    int row = nloc + j;
                    int gsl = (cbase + i4 * 2) ^ (((row >> 3) ^ row) & 7);
                    *(uint2*)&Bs[nxt][row * GBK + gsl * 8 + koff] = make_uint2(lo, hi);
                }
            }
        }
    }

#pragma unroll
    for (int mi = 0; mi < 4; ++mi) {
#pragma unroll
        for (int r = 0; r < 4; ++r) {
            int row = wm + mi * 16 + fq * 4 + r;
            int m = mt * GBM + row;
            if (m < cnt) {
                size_t ro = (size_t)(hbase + m) * HDIM + nbase + wn;
#pragma unroll
                for (int ni = 0; ni < 4; ++ni) {
                    float u  = acc[mi][ni][r];
                    float hh = u / (1.f + __expf(-u));     // silu
                    hbuf[ro + ni * 16 + fr] = f2bf(hh);
                }
            }
        }
    }
}

// down_gemm: y = h @ W2_e -> bf16 ybuf.  B = W2 [e][k=HDIM][n=DDIM] fp32.
__global__ __launch_bounds__(256) void down_gemm(
    const unsigned short* __restrict__ hbuf, const float* __restrict__ W2,
    const int* __restrict__ counts, const int* __restrict__ offsets,
    const int* __restrict__ ntiles, const int* __restrict__ tile_e,
    const int* __restrict__ tile_mt,
    unsigned short* __restrict__ ybuf)
{
    int idx = blockIdx.x;
    if (idx >= *ntiles) return;
    int e   = tile_e[idx];
    int mt  = tile_mt[idx];
    int cnt = counts[e];
    int nbase = blockIdx.y * GBN;
    const int N = DDIM;                       // B row length (n)

    __shared__ __align__(16) unsigned short As[2][GBM * GBK];
    __shared__ __align__(16) unsigned short Bs[2][GBN * GBK];

    int tid = threadIdx.x, lane = tid & 63, wv = tid >> 6;
    int kcL = ((lane & 7) ^ ((lane >> 3) & 7)) * 8;
    int hbase = offsets[e];

    const unsigned short* gA[4];
#pragma unroll
    for (int j = 0; j < 4; ++j) {
        int row = wv * 32 + j * 8 + (lane >> 3);
        int m = mt * GBM + row; if (m >= cnt) m = cnt - 1;
        gA[j] = hbuf + (size_t)(hbase + m) * HDIM + kcL;
    }

    const float* wB = W2 + (size_t)e * HDIM * DDIM;
    int ng = lane >> 2, kg = lane & 3;
    int nh = (wv & 1) * 64, kh = (wv >> 1) * 32;
    int nloc = nh + ng * 4;
    const float* gBbase = wB + (size_t)(kh + kg * 4) * N + nbase + nloc;
    int cbase = (kh >> 3) + (kg >> 1);
    int koff  = (kg & 1) * 4;

    int fr = lane & 15, fq = lane >> 4;
    int wm = (wv & 1) * 64, wn = (wv >> 1) * 64;

    floatx4 acc[4][4];
#pragma unroll
    for (int i = 0; i < 4; ++i)
#pragma unroll
        for (int j = 0; j < 4; ++j) acc[i][j] = (floatx4){0.f, 0.f, 0.f, 0.f};

    float4 bv[8];
#pragma unroll
    for (int j = 0; j < 4; ++j)
        gl_lds16(gA[j], &As[0][((wv * 4 + j) * 64 + lane) * 8]);
#pragma unroll
    for (int i4 = 0; i4 < 2; ++i4)
#pragma unroll
        for (int ld = 0; ld < 4; ++ld)
            bv[i4 * 4 + ld] = *(const float4*)(gBbase + (size_t)(i4 * 16 + ld) * N);
#pragma unroll
    for (int i4 = 0; i4 < 2; ++i4) {
#pragma unroll
        for (int j = 0; j < 4; ++j) {
            unsigned int lo = (unsigned int)f2bf(((const float*)&bv[i4 * 4 + 0])[j])
                            | ((unsigned int)f2bf(((const float*)&bv[i4 * 4 + 1])[j]) << 16);
            unsigned int hi = (unsigned int)f2bf(((const float*)&bv[i4 * 4 + 2])[j])
                            | ((unsigned int)f2bf(((const float*)&bv[i4 * 4 + 3])[j]) << 16);
            int row = nloc + j;
            int gsl = (cbase + i4 * 2) ^ (((row >> 3) ^ row) & 7);
            *(uint2*)&Bs[0][row * GBK + gsl * 8 + koff] = make_uint2(lo, hi);
        }
    }

    const int NK = HDIM / GBK;
    for (int i = 0; i < NK; ++i) {
        int cur = i & 1, nxt = cur ^ 1;
        __syncthreads();
        if (i + 1 < NK) {
            int k0 = (i + 1) * GBK;
#pragma unroll
            for (int j = 0; j < 4; ++j)
                gl_lds16(gA[j] + k0, &As[nxt][((wv * 4 + j) * 64 + lane) * 8]);
#pragma unroll
            for (int i4 = 0; i4 < 2; ++i4)
#pragma unroll
                for (int ld = 0; ld < 4; ++ld)
                    bv[i4 * 4 + ld] = *(const float4*)(gBbase + (size_t)(k0 + i4 * 16 + ld) * N);
        }
#pragma unroll
        for (int ks = 0; ks < 2; ++ks) {
            short8 af[4], bfr[4];
#pragma unroll
            for (int mi = 0; mi < 4; ++mi) {
                int row = wm + mi * 16 + fr;
                int kcs = (ks * 4 + fq) ^ (row & 7);
                af[mi] = *(const short8*)&As[cur][row * GBK + kcs * 8];
            }
#pragma unroll
            for (int ni = 0; ni < 4; ++ni) {
                int row = wn + ni * 16 + fr;
                int kcs = (ks * 4 + fq) ^ (((row >> 3) ^ row) & 7);
                bfr[ni] = *(const short8*)&Bs[cur][row * GBK + kcs * 8];
            }
#pragma unroll
            for (int mi = 0; mi < 4; ++mi)
#pragma unroll
                for (int ni = 0; ni < 4; ++ni)
                    acc[mi][ni] = __builtin_amdgcn_mfma_f32_16x16x32_bf16(
                        af[mi], bfr[ni], acc[mi][ni], 0, 0, 0);
        }
        if (i + 1 < NK) {
#pragma unroll
            for (int i4 = 0; i4 < 2; ++i4) {
#pragma unroll
                for (int j = 0; j < 4; ++j) {
                    unsigned int lo = (unsigned int)f2bf(((const float*)&bv[i4 * 4 + 0])[j])
                                    | ((unsigned int)f2bf(((const float*)&bv[i4 * 4 + 1])[j]) << 16);
                    unsigned int hi = (unsigned int)f2bf(((const float*)&bv[i4 * 4 + 2])[j])
                                    | ((unsigned int)f2bf(((const float*)&bv[i4 * 4 + 3])[j]) << 16);
                    int row = nloc + j;
                    int gsl = (cbase + i4 * 2) ^ (((row >> 3) ^ row) & 7);
                    *(uint2*)&Bs[nxt][row * GBK + gsl * 8 + koff] = make_uint2(lo, hi);
                }
            }
        }
    }

#pragma unroll
    for (int mi = 0; mi < 4; ++mi) {
#pragma unroll
        for (int r = 0; r < 4; ++r) {
            int row = wm + mi * 16 + fq * 4 + r;
            int m = mt * GBM + row;
            if (m < cnt) {
                size_t ro = (size_t)(hbase + m) * DDIM + nbase + wn;
#pragma unroll
                for (int ni = 0; ni < 4; ++ni)
                    ybuf[ro + ni * 16 + fr] = f2bf(acc[mi][ni][r]);
            }
        }
    }
}

// ---------------------------------------------------------------------------
// combine: out[t] = w0 * y[slot0] + w1 * y[slot1]  (writes every element,
// so no out-memset needed).
// ---------------------------------------------------------------------------
__global__ __launch_bounds__(256) void combine_kernel(
    const unsigned short* __restrict__ ybuf, const int* __restrict__ offsets,
    const int4* __restrict__ tinfo, const float2* __restrict__ wcomb,
    float* __restrict__ out)
{
    int t = blockIdx.x;
    int4   ti = tinfo[t];
    float2 w  = wcomb[t];
    int s0 = offsets[ti.x] + ti.y;
    int s1 = offsets[ti.z] + ti.w;
    const ushort4* y0 = (const ushort4*)(ybuf + (size_t)s0 * DDIM);
    const ushort4* y1 = (const ushort4*)(ybuf + (size_t)s1 * DDIM);
    float4* op = (float4*)(out + (size_t)t * DDIM);
#pragma unroll
    for (int i = 0; i < 2; ++i) {
        int c = threadIdx.x + i * 256;
        ushort4 a = y0[c], b = y1[c];
        float4 r;
        r.x = w.x * bf2f(a.x) + w.y * bf2f(b.x);
        r.y = w.x * bf2f(a.y) + w.y * bf2f(b.y);
        r.z = w.x * bf2f(a.z) + w.y * bf2f(b.z);
        r.w = w.x * bf2f(a.w) + w.y * bf2f(b.w);
        op[c] = r;
    }
}

// ---------------------------------------------------------------------------
// Workspace layout (bytes):
//   0         counts[16]
//   256       offsets[17]
//   512       ntiles + tile_e[80] + tile_mt[80]
//   2048      tok_list 16*4096*4      = 256 KB
//   264192    tinfo    4096*16        = 64 KB
//   329728    wcomb    4096*8         = 32 KB
//   524288    xbf      4096*2048*2    = 16 MB
//   17301504  hbuf     8192*1024*2    = 16 MB
//   34078720  ybuf     8192*2048*2    = 32 MB   (W1T/W2T regions now unused)
// ---------------------------------------------------------------------------
extern "C" void kernel_launch(void* const* d_in, const int* in_sizes, int n_in,
                              void* d_out, int out_size, void* d_ws, size_t ws_size,
                              hipStream_t stream)
{
    const float* x    = (const float*)d_in[0];
    const float* Wg   = (const float*)d_in[1];
    const float* bias = (const float*)d_in[2];
    const float* W1   = (const float*)d_in[3];
    const float* W2   = (const float*)d_in[4];
    float* out = (float*)d_out;

    char* ws = (char*)d_ws;
    int*            counts   = (int*)(ws + 0);
    int*            offsets  = (int*)(ws + 256);
    int*            ntiles   = (int*)(ws + 512);
    int*            tile_e   = (int*)(ws + 512 + 4);
    int*            tile_mt  = (int*)(ws + 512 + 4 + MAX_TILES * 4);
    int*            tok_list = (int*)(ws + 2048);
    int4*           tinfo    = (int4*)(ws + 264192);
    float2*         wcomb    = (float2*)(ws + 329728);
    unsigned short* xbf      = (unsigned short*)(ws + 524288);
    unsigned short* hbuf     = (unsigned short*)(ws + 17301504);
    unsigned short* ybuf     = (unsigned short*)(ws + 34078720);

    hipMemsetAsync(counts, 0, 64, stream);

    gate_kernel<<<dim3(T_TOK / 4), 256, 0, stream>>>(
        x, Wg, bias, counts, tok_list, tinfo, wcomb, xbf);
    scan_kernel<<<1, 64, 0, stream>>>(counts, offsets, ntiles, tile_e, tile_mt);
    up_gemm<<<dim3(MAX_TILES, HDIM / GBN), 256, 0, stream>>>(
        xbf, W1, counts, offsets, ntiles, tile_e, tile_mt, tok_list, hbuf);
    down_gemm<<<dim3(MAX_TILES, DDIM / GBN), 256, 0, stream>>>(
        hbuf, W2, counts, offsets, ntiles, tile_e, tile_mt, ybuf);
    combine_kernel<<<T_TOK, 256, 0, stream>>>(ybuf, offsets, tinfo, wcomb, out);
}

// Round 4
// 631.403 us; speedup vs baseline: 1.0967x; 1.0967x over previous
//
#include <hip/hip_runtime.h>
#include <math.h>

// Problem constants (B=4,S=1024 -> T=4096; D=2048; E=16; H=1024; top-2)
#define T_TOK 4096
#define DDIM  2048
#define HDIM  1024
#define NEXP  16
#define CAP   4096
#define GBM   128
#define GBN   128
#define GBK   64     // bf16 elems per K-tile (= 8 k-octets)
#define MAX_TILES 80 // sum ceil(cnt_e/128) <= 8192/128 + 16

typedef __attribute__((ext_vector_type(8))) short  short8;
typedef __attribute__((ext_vector_type(4))) float  floatx4;

__device__ __forceinline__ unsigned short f2bf(float f) {
    unsigned int u = __float_as_uint(f);
    u += 0x7fffu + ((u >> 16) & 1u);   // round-to-nearest-even
    return (unsigned short)(u >> 16);
}
__device__ __forceinline__ float bf2f(unsigned short u) {
    return __uint_as_float((unsigned int)u << 16);
}

__device__ __forceinline__ void gl_lds16(const void* g, void* l) {
    __builtin_amdgcn_global_load_lds(
        (const __attribute__((address_space(1))) unsigned int*)g,
        (__attribute__((address_space(3))) unsigned int*)l,
        16, 0, 0);
}

// ---------------------------------------------------------------------------
// wconv_kernel: fp32 [e][k][n] -> bf16 k-packed-8  Wp[e][k>>3][n][k&7].
// One block per (expert, k-octet): reads 8 FULL 4/8-KB fp32 rows (contiguous
// streaming), writes one 16/32-KB contiguous bf16 region (streaming).
// No sub-KB scattered HBM chunks anywhere -> should run near copy BW,
// unlike the tile transposes (128-512 B chunks -> 1.3 TB/s plateau).
// ---------------------------------------------------------------------------
__global__ __launch_bounds__(256) void wconv_kernel(
    const float* __restrict__ W1, const float* __restrict__ W2,
    unsigned short* __restrict__ W1p, unsigned short* __restrict__ W2p)
{
    __shared__ __align__(16) unsigned short Lp[8 * 2048];   // 32 KB (W2 max)
    int bid = blockIdx.x;
    const float* src; unsigned short* dst; int N;
    if (bid < 4096) {                     // W1: K=2048, N=1024 (16*256 blocks)
        int e = bid >> 8, oct = bid & 255;
        src = W1  + ((size_t)e * 2048 + oct * 8) * 1024;
        dst = W1p + ((size_t)e * 2048 + oct * 8) * 1024;
        N = 1024;
    } else {                              // W2: K=1024, N=2048 (16*128 blocks)
        int b2 = bid - 4096;
        int e = b2 >> 7, oct = b2 & 127;
        src = W2  + ((size_t)e * 1024 + oct * 8) * 2048;
        dst = W2p + ((size_t)e * 1024 + oct * 8) * 2048;
        N = 2048;
    }
    int t = threadIdx.x;
    int r = t >> 5, l32 = t & 31;         // 8 rows x 32 threads/row

    // load + convert -> LDS [r][N] bf16 (ushort4 writes, 2-way banks = free)
    for (int i = 0; i < N / 128; ++i) {
        int c4 = l32 + i * 32;            // float4 column (coalesced)
        float4 v = *(const float4*)(src + (size_t)r * N + c4 * 4);
        ushort4 s;
        s.x = f2bf(v.x); s.y = f2bf(v.y); s.z = f2bf(v.z); s.w = f2bf(v.w);
        *(ushort4*)&Lp[r * N + c4 * 4] = s;
    }
    __syncthreads();

    // pack: column n -> short8 (8 consecutive k), contiguous 1-KB wave stores
    for (int q = 0; q < N / 256; ++q) {
        int n = t + q * 256;
        short8 o;
#pragma unroll
        for (int r8 = 0; r8 < 8; ++r8) o[r8] = (short)Lp[r8 * N + n];
        *(short8*)(dst + (size_t)n * 8) = o;
    }
}

// ---------------------------------------------------------------------------
// gate_kernel: one wave per token; sigmoid gating, top-2, token lists,
// x -> bf16 (xbf).
// ---------------------------------------------------------------------------
__global__ __launch_bounds__(256) void gate_kernel(
    const float* __restrict__ x, const float* __restrict__ Wg,
    const float* __restrict__ bias,
    int* __restrict__ counts, int* __restrict__ tok_list,
    int4* __restrict__ tinfo, float2* __restrict__ wcomb,
    unsigned short* __restrict__ xbf)
{
    int tb   = blockIdx.x;                 // 0..1023
    int wv   = threadIdx.x >> 6;
    int lane = threadIdx.x & 63;
    int t    = tb * 4 + wv;

    const float4* xp4 = (const float4*)x + (size_t)t * (DDIM / 4);
    ushort4* xbp4 = (ushort4*)(xbf + (size_t)t * DDIM);
    const float4* wg4 = (const float4*)Wg;

    float acc[NEXP];
#pragma unroll
    for (int e = 0; e < NEXP; ++e) acc[e] = 0.f;

    for (int it = 0; it < DDIM / 4 / 64; ++it) {
        int d4 = it * 64 + lane;
        float4 xv = xp4[d4];
        ushort4 xs;
        xs.x = f2bf(xv.x); xs.y = f2bf(xv.y);
        xs.z = f2bf(xv.z); xs.w = f2bf(xv.w);
        xbp4[d4] = xs;
#pragma unroll
        for (int e = 0; e < NEXP; ++e) {
            float4 wvv = wg4[e * (DDIM / 4) + d4];
            acc[e] += xv.x * wvv.x + xv.y * wvv.y + xv.z * wvv.z + xv.w * wvv.w;
        }
    }
#pragma unroll
    for (int e = 0; e < NEXP; ++e) {
        float v = acc[e];
#pragma unroll
        for (int off = 32; off > 0; off >>= 1) v += __shfl_xor(v, off, 64);
        acc[e] = v;
    }
    if (lane == 0) {
        float s[NEXP];
#pragma unroll
        for (int e = 0; e < NEXP; ++e)
            s[e] = 1.f / (1.f + expf(-(acc[e] + bias[e])));
        int i0 = 0;
#pragma unroll
        for (int e = 1; e < NEXP; ++e) if (s[e] > s[i0]) i0 = e;
        int i1 = (i0 == 0) ? 1 : 0;
        for (int e = 0; e < NEXP; ++e)
            if (e != i0 && s[e] > s[i1]) i1 = e;
        float denom = s[i0] + s[i1] + 1e-6f;
        int p0 = atomicAdd(&counts[i0], 1);
        tok_list[i0 * CAP + p0] = t;
        int p1 = atomicAdd(&counts[i1], 1);
        tok_list[i1 * CAP + p1] = t;
        tinfo[t] = make_int4(i0, p0, i1, p1);
        wcomb[t] = make_float2(s[i0] / denom, s[i1] / denom);
    }
}

// ---------------------------------------------------------------------------
// scan: single wave, shuffle prefix-scan.
// ---------------------------------------------------------------------------
__global__ void scan_kernel(const int* __restrict__ counts, int* __restrict__ offsets,
                            int* __restrict__ ntiles, int* __restrict__ tile_e,
                            int* __restrict__ tile_mt)
{
    int lane = threadIdx.x;                         // 64 threads
    int c = (lane < NEXP) ? counts[lane] : 0;
    int incl = c;
#pragma unroll
    for (int d = 1; d < 64; d <<= 1) {
        int v = __shfl_up(incl, d, 64);
        if (lane >= d) incl += v;
    }
    if (lane < NEXP) offsets[lane] = incl - c;
    if (lane == NEXP - 1) offsets[NEXP] = incl;

    int nt_e = (lane < NEXP) ? ((c + GBM - 1) / GBM) : 0;
    int tincl = nt_e;
#pragma unroll
    for (int d = 1; d < 64; d <<= 1) {
        int v = __shfl_up(tincl, d, 64);
        if (lane >= d) tincl += v;
    }
    int tbase = tincl - nt_e;
    if (lane < NEXP) {
        for (int i = 0; i < nt_e; ++i) {
            tile_e[tbase + i]  = lane;
            tile_mt[tbase + i] = i;
        }
        if (lane == NEXP - 1) *ntiles = tbase + nt_e;
    }
}

// ---------------------------------------------------------------------------
// GEMMs: A (bf16 activations) and B (bf16 k-packed-8 weights) BOTH staged via
// gl_lds16, linear LDS, conflict-free b128 fragment reads (B needs no
// swizzle: octet-major layout makes every fragment 16 B contiguous, and
// 16-lane groups read 256-B contiguous runs). XCD-chunk swizzle on the
// linearized (tile, n-slice) index for L2 panel sharing.
// ---------------------------------------------------------------------------

// up_gemm: h = silu(Xg @ W1_e) -> bf16 hbuf.  Grid 640 = 8 XCD x 80.
__global__ __launch_bounds__(256) void up_gemm(
    const unsigned short* __restrict__ xbf, const unsigned short* __restrict__ W1p,
    const int* __restrict__ counts, const int* __restrict__ offsets,
    const int* __restrict__ ntiles, const int* __restrict__ tile_e,
    const int* __restrict__ tile_mt,
    const int* __restrict__ tok_list, unsigned short* __restrict__ hbuf)
{
    int w = blockIdx.x;
    int swz = (w & 7) * 80 + (w >> 3);        // bijective: 640 = 8*80
    int idx = swz >> 3;                       // m-tile  (8 n-slices)
    int nbase = (swz & 7) * GBN;
    if (idx >= *ntiles) return;
    int e   = tile_e[idx];
    int mt  = tile_mt[idx];
    int cnt = counts[e];

    __shared__ __align__(16) unsigned short As[2][GBM * GBK];
    __shared__ __align__(16) unsigned short Bs[2][GBN * GBK];

    int tid = threadIdx.x, lane = tid & 63, wv = tid >> 6;
    int kcL = ((lane & 7) ^ ((lane >> 3) & 7)) * 8;
    int hbase = offsets[e];

    const unsigned short* gA[4];
#pragma unroll
    for (int j = 0; j < 4; ++j) {
        int row = wv * 32 + j * 8 + (lane >> 3);
        int m = mt * GBM + row; if (m >= cnt) m = cnt - 1;
        int tok = tok_list[e * CAP + m];
        gA[j] = xbf + (size_t)tok * DDIM + kcL;
    }

    // B segments: s = wv*4+j covers octet o=s>>1, n-half (s&1)*64
    const unsigned short* gB[4];
#pragma unroll
    for (int j = 0; j < 4; ++j) {
        int s = wv * 4 + j;
        gB[j] = W1p + (size_t)e * DDIM * HDIM
              + ((size_t)(s >> 1) * HDIM + nbase + (s & 1) * 64 + lane) * 8;
    }
    const size_t kstepB = (size_t)GBK * HDIM;   // 8 octets * N * 8 shorts

    int fr = lane & 15, fq = lane >> 4;
    int wm = (wv & 1) * 64, wn = (wv >> 1) * 64;

    floatx4 acc[4][4];
#pragma unroll
    for (int i = 0; i < 4; ++i)
#pragma unroll
        for (int j = 0; j < 4; ++j) acc[i][j] = (floatx4){0.f, 0.f, 0.f, 0.f};

#pragma unroll
    for (int j = 0; j < 4; ++j)
        gl_lds16(gA[j], &As[0][((wv * 4 + j) * 64 + lane) * 8]);
#pragma unroll
    for (int j = 0; j < 4; ++j)
        gl_lds16(gB[j], &Bs[0][((wv * 4 + j) * 64 + lane) * 8]);

    const int NK = DDIM / GBK;
    for (int i = 0; i < NK; ++i) {
        int cur = i & 1, nxt = cur ^ 1;
        __syncthreads();
        if (i + 1 < NK) {
            int k0 = (i + 1) * GBK;
#pragma unroll
            for (int j = 0; j < 4; ++j)
                gl_lds16(gA[j] + k0, &As[nxt][((wv * 4 + j) * 64 + lane) * 8]);
#pragma unroll
            for (int j = 0; j < 4; ++j)
                gl_lds16(gB[j] + (size_t)(i + 1) * kstepB,
                         &Bs[nxt][((wv * 4 + j) * 64 + lane) * 8]);
        }
#pragma unroll
        for (int ks = 0; ks < 2; ++ks) {
            short8 af[4], bfr[4];
#pragma unroll
            for (int mi = 0; mi < 4; ++mi) {
                int row = wm + mi * 16 + fr;
                int kcs = (ks * 4 + fq) ^ (row & 7);
                af[mi] = *(const short8*)&As[cur][row * GBK + kcs * 8];
            }
#pragma unroll
            for (int ni = 0; ni < 4; ++ni) {
                int row = wn + ni * 16 + fr;
                bfr[ni] = *(const short8*)&Bs[cur][((ks * 4 + fq) * GBN + row) * 8];
            }
#pragma unroll
            for (int mi = 0; mi < 4; ++mi)
#pragma unroll
                for (int ni = 0; ni < 4; ++ni)
                    acc[mi][ni] = __builtin_amdgcn_mfma_f32_16x16x32_bf16(
                        af[mi], bfr[ni], acc[mi][ni], 0, 0, 0);
        }
    }

#pragma unroll
    for (int mi = 0; mi < 4; ++mi) {
#pragma unroll
        for (int r = 0; r < 4; ++r) {
            int row = wm + mi * 16 + fq * 4 + r;
            int m = mt * GBM + row;
            if (m < cnt) {
                size_t ro = (size_t)(hbase + m) * HDIM + nbase + wn;
#pragma unroll
                for (int ni = 0; ni < 4; ++ni) {
                    float u  = acc[mi][ni][r];
                    float hh = u / (1.f + __expf(-u));     // silu
                    hbuf[ro + ni * 16 + fr] = f2bf(hh);
                }
            }
        }
    }
}

// down_gemm: y = h @ W2_e -> bf16 ybuf.  Grid 1280 = 8 XCD x 160.
__global__ __launch_bounds__(256) void down_gemm(
    const unsigned short* __restrict__ hbuf, const unsigned short* __restrict__ W2p,
    const int* __restrict__ counts, const int* __restrict__ offsets,
    const int* __restrict__ ntiles, const int* __restrict__ tile_e,
    const int* __restrict__ tile_mt,
    unsigned short* __restrict__ ybuf)
{
    int w = blockIdx.x;
    int swz = (w & 7) * 160 + (w >> 3);       // bijective: 1280 = 8*160
    int idx = swz >> 4;                       // m-tile (16 n-slices)
    int nbase = (swz & 15) * GBN;
    if (idx >= *ntiles) return;
    int e   = tile_e[idx];
    int mt  = tile_mt[idx];
    int cnt = counts[e];

    __shared__ __align__(16) unsigned short As[2][GBM * GBK];
    __shared__ __align__(16) unsigned short Bs[2][GBN * GBK];

    int tid = threadIdx.x, lane = tid & 63, wv = tid >> 6;
    int kcL = ((lane & 7) ^ ((lane >> 3) & 7)) * 8;
    int hbase = offsets[e];

    const unsigned short* gA[4];
#pragma unroll
    for (int j = 0; j < 4; ++j) {
        int row = wv * 32 + j * 8 + (lane >> 3);
        int m = mt * GBM + row; if (m >= cnt) m = cnt - 1;
        gA[j] = hbuf + (size_t)(hbase + m) * HDIM + kcL;
    }

    const unsigned short* gB[4];
#pragma unroll
    for (int j = 0; j < 4; ++j) {
        int s = wv * 4 + j;
        gB[j] = W2p + (size_t)e * HDIM * DDIM
              + ((size_t)(s >> 1) * DDIM + nbase + (s & 1) * 64 + lane) * 8;
    }
    const size_t kstepB = (size_t)GBK * DDIM;

    int fr = lane & 15, fq = lane >> 4;
    int wm = (wv & 1) * 64, wn = (wv >> 1) * 64;

    floatx4 acc[4][4];
#pragma unroll
    for (int i = 0; i < 4; ++i)
#pragma unroll
        for (int j = 0; j < 4; ++j) acc[i][j] = (floatx4){0.f, 0.f, 0.f, 0.f};

#pragma unroll
    for (int j = 0; j < 4; ++j)
        gl_lds16(gA[j], &As[0][((wv * 4 + j) * 64 + lane) * 8]);
#pragma unroll
    for (int j = 0; j < 4; ++j)
        gl_lds16(gB[j], &Bs[0][((wv * 4 + j) * 64 + lane) * 8]);

    const int NK = HDIM / GBK;
    for (int i = 0; i < NK; ++i) {
        int cur = i & 1, nxt = cur ^ 1;
        __syncthreads();
        if (i + 1 < NK) {
            int k0 = (i + 1) * GBK;
#pragma unroll
            for (int j = 0; j < 4; ++j)
                gl_lds16(gA[j] + k0, &As[nxt][((wv * 4 + j) * 64 + lane) * 8]);
#pragma unroll
            for (int j = 0; j < 4; ++j)
                gl_lds16(gB[j] + (size_t)(i + 1) * kstepB,
                         &Bs[nxt][((wv * 4 + j) * 64 + lane) * 8]);
        }
#pragma unroll
        for (int ks = 0; ks < 2; ++ks) {
            short8 af[4], bfr[4];
#pragma unroll
            for (int mi = 0; mi < 4; ++mi) {
                int row = wm + mi * 16 + fr;
                int kcs = (ks * 4 + fq) ^ (row & 7);
                af[mi] = *(const short8*)&As[cur][row * GBK + kcs * 8];
            }
#pragma unroll
            for (int ni = 0; ni < 4; ++ni) {
                int row = wn + ni * 16 + fr;
                bfr[ni] = *(const short8*)&Bs[cur][((ks * 4 + fq) * GBN + row) * 8];
            }
#pragma unroll
            for (int mi = 0; mi < 4; ++mi)
#pragma unroll
                for (int ni = 0; ni < 4; ++ni)
                    acc[mi][ni] = __builtin_amdgcn_mfma_f32_16x16x32_bf16(
                        af[mi], bfr[ni], acc[mi][ni], 0, 0, 0);
        }
    }

#pragma unroll
    for (int mi = 0; mi < 4; ++mi) {
#pragma unroll
        for (int r = 0; r < 4; ++r) {
            int row = wm + mi * 16 + fq * 4 + r;
            int m = mt * GBM + row;
            if (m < cnt) {
                size_t ro = (size_t)(hbase + m) * DDIM + nbase + wn;
#pragma unroll
                for (int ni = 0; ni < 4; ++ni)
                    ybuf[ro + ni * 16 + fr] = f2bf(acc[mi][ni][r]);
            }
        }
    }
}

// ---------------------------------------------------------------------------
// combine: out[t] = w0 * y[slot0] + w1 * y[slot1].
// ---------------------------------------------------------------------------
__global__ __launch_bounds__(256) void combine_kernel(
    const unsigned short* __restrict__ ybuf, const int* __restrict__ offsets,
    const int4* __restrict__ tinfo, const float2* __restrict__ wcomb,
    float* __restrict__ out)
{
    int t = blockIdx.x;
    int4   ti = tinfo[t];
    float2 w  = wcomb[t];
    int s0 = offsets[ti.x] + ti.y;
    int s1 = offsets[ti.z] + ti.w;
    const ushort4* y0 = (const ushort4*)(ybuf + (size_t)s0 * DDIM);
    const ushort4* y1 = (const ushort4*)(ybuf + (size_t)s1 * DDIM);
    float4* op = (float4*)(out + (size_t)t * DDIM);
#pragma unroll
    for (int i = 0; i < 2; ++i) {
        int c = threadIdx.x + i * 256;
        ushort4 a = y0[c], b = y1[c];
        float4 r;
        r.x = w.x * bf2f(a.x) + w.y * bf2f(b.x);
        r.y = w.x * bf2f(a.y) + w.y * bf2f(b.y);
        r.z = w.x * bf2f(a.z) + w.y * bf2f(b.z);
        r.w = w.x * bf2f(a.w) + w.y * bf2f(b.w);
        op[c] = r;
    }
}

// ---------------------------------------------------------------------------
// Workspace layout (bytes):
//   0         counts[16]
//   256       offsets[17]
//   512       ntiles + tile_e[80] + tile_mt[80]
//   2048      tok_list 16*4096*4      = 256 KB
//   264192    tinfo    4096*16        = 64 KB
//   329728    wcomb    4096*8         = 32 KB
//   524288    xbf      4096*2048*2    = 16 MB
//   17301504  hbuf     8192*1024*2    = 16 MB
//   34078720  ybuf     8192*2048*2    = 32 MB
//   67633152  W1p      16*2048*1024*2 = 64 MB   (bf16 k-packed-8)
//   134742016 W2p      16*1024*2048*2 = 64 MB   (bf16 k-packed-8)
// ---------------------------------------------------------------------------
extern "C" void kernel_launch(void* const* d_in, const int* in_sizes, int n_in,
                              void* d_out, int out_size, void* d_ws, size_t ws_size,
                              hipStream_t stream)
{
    const float* x    = (const float*)d_in[0];
    const float* Wg   = (const float*)d_in[1];
    const float* bias = (const float*)d_in[2];
    const float* W1   = (const float*)d_in[3];
    const float* W2   = (const float*)d_in[4];
    float* out = (float*)d_out;

    char* ws = (char*)d_ws;
    int*            counts   = (int*)(ws + 0);
    int*            offsets  = (int*)(ws + 256);
    int*            ntiles   = (int*)(ws + 512);
    int*            tile_e   = (int*)(ws + 512 + 4);
    int*            tile_mt  = (int*)(ws + 512 + 4 + MAX_TILES * 4);
    int*            tok_list = (int*)(ws + 2048);
    int4*           tinfo    = (int4*)(ws + 264192);
    float2*         wcomb    = (float2*)(ws + 329728);
    unsigned short* xbf      = (unsigned short*)(ws + 524288);
    unsigned short* hbuf     = (unsigned short*)(ws + 17301504);
    unsigned short* ybuf     = (unsigned short*)(ws + 34078720);
    unsigned short* W1p      = (unsigned short*)(ws + 67633152);
    unsigned short* W2p      = (unsigned short*)(ws + 134742016);

    hipMemsetAsync(counts, 0, 64, stream);

    gate_kernel<<<dim3(T_TOK / 4), 256, 0, stream>>>(
        x, Wg, bias, counts, tok_list, tinfo, wcomb, xbf);
    wconv_kernel<<<dim3(4096 + 2048), 256, 0, stream>>>(W1, W2, W1p, W2p);
    scan_kernel<<<1, 64, 0, stream>>>(counts, offsets, ntiles, tile_e, tile_mt);
    up_gemm<<<dim3(MAX_TILES * 8), 256, 0, stream>>>(
        xbf, W1p, counts, offsets, ntiles, tile_e, tile_mt, tok_list, hbuf);
    down_gemm<<<dim3(MAX_TILES * 16), 256, 0, stream>>>(
        hbuf, W2p, counts, offsets, ntiles, tile_e, tile_mt, ybuf);
    combine_kernel<<<T_TOK, 256, 0, stream>>>(ybuf, offsets, tinfo, wcomb, out);
}